// Round 7
// baseline (296.669 us; speedup 1.0000x reference)
//
#include <hip/hip_runtime.h>
#include <hip/hip_fp16.h>

#define BB 32
#define HH 512
#define WW 512
#define NQROW (WW / 4)            // 128 float4 per row
#define NPIX_F 8388608.0f         // 32*512*512
#define QPAD 4

// ---- fused kernel geometry ----
#define RF 16                     // output rows per wave
#define NSTRF (HH / RF)           // 32 stripes
#define NBF (BB * NSTRF * 2)      // 2048 blocks (1 wave each)
#define NROWSF (RF + 30)          // 46 input rows per stripe
#define CQH 64                    // owned quads per column half (256 cols)
#define NQPH (CQH + 2 * QPAD)     // 72 quads incl halo
#define WS_NEED_F ((size_t)NBF * 16)   // 32 KiB of float4 partials

__device__ __forceinline__ void elemwise4(const float h0, const float h1,
                                          const float h2, const float h3,
                                          const float4 t, const float4 p,
                                          float& a_bce, float& a_w,
                                          float& a_i, float& a_u)
{
    const float hv[4] = {h0, h1, h2, h3};
    const float tv[4] = {t.x, t.y, t.z, t.w};
    const float pv[4] = {p.x, p.y, p.z, p.w};
    const float inv961 = (1.0f / 961.0f);
    #pragma unroll
    for (int j = 0; j < 4; ++j) {
        const float ap = hv[j] * inv961;
        const float w  = fmaf(5.0f, fabsf(ap - tv[j]), 1.0f);
        const float pr = pv[j];
        const float ea = __expf(-fabsf(pr));                  // exp(-|pr|)
        const float iv = __builtin_amdgcn_rcpf(1.0f + ea);
        const float pp = (pr >= 0.0f) ? iv : (1.0f - iv);     // sigmoid
        const float sp = fmaxf(pr, 0.0f) + __logf(1.0f + ea); // softplus
        a_bce += sp - pr * tv[j];
        a_w   += w;
        a_i   += pp * tv[j] * w;
        a_u   += (pp + tv[j]) * w;
    }
}

// ---- Fused: horizontal 31-sum per input row (LDS exchange), vertical
// running sum over h-rows in registers, elementwise + per-block partial.
// One wave per (image, 16-row stripe, column half). No V workspace.
__global__ __launch_bounds__(64, 2)
void fused_rows_kernel(const float* __restrict__ pred,
                       const float* __restrict__ targ,
                       float4* __restrict__ part)
{
    const int lane = threadIdx.x;
    const int bi = blockIdx.x;                 // 2048
    const int halfc  = bi & 1;
    const int stripe = (bi >> 1) & (NSTRF - 1);
    const int b      = bi >> 6;
    const int r0  = stripe * RF;
    const int cq0 = halfc * CQH;
    const int q   = cq0 + lane;                // owned quad (global col/4)

    __shared__ float4 ebuf[2][NQPH];           // raw rows, double-buffered
    __shared__ float  locq[2][NQPH];           // per-quad sums

    const float4* t4 = (const float4*)(targ + (size_t)b * HH * WW);
    const float4* p4 = (const float4*)(pred + (size_t)b * HH * WW);
    const float4 Z4 = make_float4(0.f, 0.f, 0.f, 0.f);

    // halo quads handled by lanes 0..7 (stateless loads only)
    const int hq = (lane < 4) ? (cq0 - QPAD + lane) : (cq0 + CQH + (lane - 4));
    const bool hq_ok = (lane < 8) && (hq >= 0) && (hq < NQROW);
    const int hslot = (lane < 4) ? lane : (CQH + QPAD + (lane - 4));

    auto ldo = [&](int k) -> float4 {          // owned quad, input row r0-15+k
        const int yy = r0 - 15 + k;
        return (k < NROWSF && yy >= 0 && yy < HH)
                   ? t4[(size_t)yy * NQROW + q] : Z4;
    };
    auto ldh = [&](int k) -> float4 {          // halo quad
        const int yy = r0 - 15 + k;
        return (k < NROWSF && hq_ok && yy >= 0 && yy < HH)
                   ? t4[(size_t)yy * NQROW + hq] : Z4;
    };

    // depth-8 prefetch rings for the raw target rows
    float4 buf[8], hbuf[8];
    #pragma unroll
    for (int i = 0; i < 8; ++i) { buf[i] = ldo(i); hbuf[i] = ldh(i); }

    float4 sv[RF];                             // h-rows that will exit
    float4 tf[4], pf[4];                       // t/p prefetch ring (lookahead 3)
    float v0 = 0.f, v1 = 0.f, v2 = 0.f, v3 = 0.f;
    float a_bce = 0.f, a_w = 0.f, a_i = 0.f, a_u = 0.f;

    #pragma unroll
    for (int k = 0; k < NROWSF; ++k) {         // input row r0-15+k
        const float4 e  = buf[k & 7];
        const float4 eh = hbuf[k & 7];
        buf[k & 7]  = ldo(k + 8);
        hbuf[k & 7] = ldh(k + 8);

        // t/p prefetch: output j = k-27 issued here, consumed at k = j+30
        if (k >= 27 && k < 27 + RF) {
            const int j = k - 27;
            const size_t off = (size_t)(r0 + j) * NQROW + q;
            tf[j & 3] = t4[off];
            pf[j & 3] = p4[off];
        }

        const int bf = k & 1;
        ebuf[bf][QPAD + lane] = e;
        locq[bf][QPAD + lane] = e.x + e.y + e.z + e.w;
        if (lane < 8) {
            ebuf[bf][hslot] = eh;
            locq[bf][hslot] = eh.x + eh.y + eh.z + eh.w;
        }
        __builtin_amdgcn_wave_barrier();       // single-wave LDS exchange

        // horizontal 31-sums for owned cols 4q..4q+3 (verified r1-r6)
        float F = 0.f;
        #pragma unroll
        for (int d = -3; d <= 3; ++d) F += locq[bf][QPAD + lane + d];
        const float4 L = ebuf[bf][lane];
        const float4 U = ebuf[bf][lane + 2 * QPAD];
        const float h0 = F + L.y + L.z + L.w;
        const float h1 = F + L.z + L.w + U.x;
        const float h2 = F + L.w + U.x + U.y;
        const float h3 = F + U.x + U.y + U.z;

        if (k < RF) sv[k] = make_float4(h0, h1, h2, h3);
        v0 += h0; v1 += h1; v2 += h2; v3 += h3;

        if (k >= 30) {
            const int j = k - 30;              // output row y = r0 + j
            elemwise4(v0, v1, v2, v3, tf[j & 3], pf[j & 3],
                      a_bce, a_w, a_i, a_u);
            const float4 s = sv[j];            // h-row y-15 exits
            v0 -= s.x; v1 -= s.y; v2 -= s.z; v3 -= s.w;
        }
    }

    #pragma unroll
    for (int off = 32; off > 0; off >>= 1) {
        a_bce += __shfl_down(a_bce, off, 64);
        a_w   += __shfl_down(a_w,   off, 64);
        a_i   += __shfl_down(a_i,   off, 64);
        a_u   += __shfl_down(a_u,   off, 64);
    }
    if (lane == 0) part[bi] = make_float4(a_bce, a_w, a_i, a_u);
}

// ---- Finalize: 64 partials per image -> per-image sums -> scalar --------
__global__ __launch_bounds__(1024)
void finalize3_kernel(const float4* __restrict__ part, float* __restrict__ out)
{
    const int lane = threadIdx.x & 63;
    const int w    = threadIdx.x >> 6;         // 16 waves, 2 images each
    __shared__ float4 sums[BB];

    #pragma unroll
    for (int s = 0; s < 2; ++s) {
        const int img = w * 2 + s;
        float4 acc = part[img * 64 + lane];    // exactly one partial per lane
        #pragma unroll
        for (int off = 32; off > 0; off >>= 1) {
            acc.x += __shfl_down(acc.x, off, 64);
            acc.y += __shfl_down(acc.y, off, 64);
            acc.z += __shfl_down(acc.z, off, 64);
            acc.w += __shfl_down(acc.w, off, 64);
        }
        if (lane == 0) sums[img] = acc;
    }
    __syncthreads();

    if (w == 0) {
        float bsum = (lane < BB) ? sums[lane].x : 0.f;
        #pragma unroll
        for (int off = 32; off > 0; off >>= 1) bsum += __shfl_down(bsum, off, 64);
        const float bce = __shfl(bsum, 0, 64) * (1.0f / NPIX_F);

        float val = 0.f;
        if (lane < BB) {
            const float wsum  = sums[lane].y;
            const float inter = sums[lane].z;
            const float uni   = sums[lane].w;
            const float w_bce = (wsum * bce + 1e-8f) / (wsum + 1e-8f);
            const float w_iou = 1.0f - (inter + 1.0f + 1e-8f) / (uni - inter + 1.0f + 1e-8f);
            val = w_bce + w_iou;
        }
        #pragma unroll
        for (int off = 32; off > 0; off >>= 1) val += __shfl_down(val, off, 64);
        if (lane == 0) out[0] = val * (1.0f / BB);
    }
}

// ================= fallback (validated round-2 fused path) ===============
#define PADK 15
#define RROWS 32
#define NSTRIPES (HH / RROWS)
#define NCH 2
#define COLS (WW / NCH)
#define CQ (COLS / 4)
#define FNQP (CQ + 2 * QPAD)
#define NSTEPS (RROWS + 2 * PADK)

__global__ __launch_bounds__(64)
void fused_pool_loss_kernel(const float* __restrict__ pred,
                            const float* __restrict__ targ,
                            float* __restrict__ ws)
{
    const int lane = threadIdx.x;
    const int bi   = blockIdx.x;
    const int half   = bi & 1;
    const int stripe = (bi >> 1) & (NSTRIPES - 1);
    const int b      = bi >> 5;
    const int r0  = stripe * RROWS;
    const int cq0 = half * CQ;

    __shared__ __half2 ring[31][2][64];
    __shared__ float4  ebuf[2][FNQP];
    __shared__ float   locq[2][FNQP];

    {
        const __half2 z2 = __floats2half2_rn(0.f, 0.f);
        __half2* rp = &ring[0][0][0];
        for (int i = lane; i < 31 * 2 * 64; i += 64) rp[i] = z2;
    }
    __builtin_amdgcn_wave_barrier();

    const float4* targ4 = (const float4*)(targ + (size_t)b * HH * WW);
    const float4* pred4 = (const float4*)(pred + (size_t)b * HH * WW);
    const float4 Z4 = make_float4(0.f, 0.f, 0.f, 0.f);

    const int hq = (lane < 4) ? (cq0 - QPAD + lane) : (cq0 + CQ + (lane - 4));
    const bool hq_ok = (lane < 8) && (hq >= 0) && (hq < NQROW);
    const int hslot = (lane < 4) ? lane : (CQ + QPAD + (lane - 4));

    auto ld_row = [&](int step, float4& m, float4& h) {
        m = Z4; h = Z4;
        const int yy = r0 - PADK + step;
        if (step < NSTEPS && yy >= 0 && yy < HH) {
            const float4* rp = targ4 + (size_t)yy * NQROW;
            m = rp[cq0 + lane];
            if (hq_ok) h = rp[hq];
        }
    };

    float vacc0 = 0.f, vacc1 = 0.f, vacc2 = 0.f, vacc3 = 0.f;
    float a_bce = 0.f, a_w = 0.f, a_i = 0.f, a_u = 0.f;
    int slot = 0;

    float4 e_p0, e_p1, h_p0, h_p1;
    ld_row(0, e_p0, h_p0);
    ld_row(1, e_p1, h_p1);
    float4 t_p0 = Z4, t_p1 = Z4, p_p0 = Z4, p_p1 = Z4;

    for (int step = 0; step < NSTEPS; ++step) {
        const float4 e  = e_p0;  e_p0 = e_p1;
        const float4 eh = h_p0;  h_p0 = h_p1;
        ld_row(step + 2, e_p1, h_p1);

        const float4 tcur = t_p0, pcur = p_p0;
        t_p0 = t_p1; p_p0 = p_p1;
        {
            const int s2 = step + 2;
            if (s2 >= 2 * PADK && s2 < NSTEPS) {
                const size_t off = (size_t)(r0 + (s2 - 2 * PADK)) * NQROW + cq0 + lane;
                t_p1 = targ4[off];
                p_p1 = pred4[off];
            }
        }

        const int bf = step & 1;
        ebuf[bf][QPAD + lane] = e;
        locq[bf][QPAD + lane] = e.x + e.y + e.z + e.w;
        if (lane < 8) {
            ebuf[bf][hslot] = eh;
            locq[bf][hslot] = eh.x + eh.y + eh.z + eh.w;
        }
        __builtin_amdgcn_wave_barrier();

        float F = 0.f;
        #pragma unroll
        for (int k = -3; k <= 3; ++k) F += locq[bf][lane + QPAD + k];
        const float4 L = ebuf[bf][lane];
        const float4 U = ebuf[bf][lane + 2 * QPAD];
        const float h0 = F + L.y + L.z + L.w;
        const float h1 = F + L.z + L.w + U.x;
        const float h2 = F + L.w + U.x + U.y;
        const float h3 = F + U.x + U.y + U.z;

        const __half2 n01 = __floats2half2_rn(h0, h1);
        const __half2 n23 = __floats2half2_rn(h2, h3);
        const __half2 o01 = ring[slot][0][lane];
        const __half2 o23 = ring[slot][1][lane];
        ring[slot][0][lane] = n01;
        ring[slot][1][lane] = n23;
        const float2 nf01 = __half22float2(n01), nf23 = __half22float2(n23);
        const float2 of01 = __half22float2(o01), of23 = __half22float2(o23);
        vacc0 += nf01.x - of01.x;
        vacc1 += nf01.y - of01.y;
        vacc2 += nf23.x - of23.x;
        vacc3 += nf23.y - of23.y;
        slot = (slot == 30) ? 0 : (slot + 1);

        if (step >= 2 * PADK) {
            elemwise4(vacc0, vacc1, vacc2, vacc3, tcur, pcur, a_bce, a_w, a_i, a_u);
        }
    }

    #pragma unroll
    for (int off = 32; off > 0; off >>= 1) {
        a_bce += __shfl_down(a_bce, off, 64);
        a_w   += __shfl_down(a_w,   off, 64);
        a_i   += __shfl_down(a_i,   off, 64);
        a_u   += __shfl_down(a_u,   off, 64);
    }
    if (lane == 0) {
        atomicAdd(&ws[0],      a_bce);
        atomicAdd(&ws[1 + b],  a_w);
        atomicAdd(&ws[33 + b], a_i);
        atomicAdd(&ws[65 + b], a_u);
    }
}

__global__ void finalize_kernel(const float* __restrict__ ws, float* __restrict__ out)
{
    const int i = threadIdx.x;
    float val = 0.f;
    if (i < BB) {
        const float bce   = ws[0] * (1.0f / NPIX_F);
        const float wsum  = ws[1 + i];
        const float inter = ws[33 + i];
        const float uni   = ws[65 + i];
        const float w_bce = (wsum * bce + 1e-8f) / (wsum + 1e-8f);
        const float w_iou = 1.0f - (inter + 1.0f + 1e-8f) / (uni - inter + 1.0f + 1e-8f);
        val = w_bce + w_iou;
    }
    #pragma unroll
    for (int off = 32; off > 0; off >>= 1) val += __shfl_down(val, off, 64);
    if (i == 0) out[0] = val * (1.0f / BB);
}

extern "C" void kernel_launch(void* const* d_in, const int* in_sizes, int n_in,
                              void* d_out, int out_size, void* d_ws, size_t ws_size,
                              hipStream_t stream)
{
    (void)in_sizes; (void)n_in; (void)out_size;
    const float* pred = (const float*)d_in[0];   // y_pred
    const float* targ = (const float*)d_in[1];   // y_target
    float* out = (float*)d_out;

    if (ws_size >= WS_NEED_F) {
        float4* part = (float4*)d_ws;
        hipLaunchKernelGGL(fused_rows_kernel, dim3(NBF), dim3(64), 0, stream,
                           pred, targ, part);
        hipLaunchKernelGGL(finalize3_kernel, dim3(1), dim3(1024), 0, stream,
                           part, out);
    } else {
        float* ws = (float*)d_ws;
        hipMemsetAsync(ws, 0, 97 * sizeof(float), stream);
        hipLaunchKernelGGL(fused_pool_loss_kernel,
                           dim3(BB * NSTRIPES * NCH), dim3(64), 0, stream,
                           pred, targ, ws);
        hipLaunchKernelGGL(finalize_kernel, dim3(1), dim3(64), 0, stream, ws, out);
    }
}

// Round 8
// 131.252 us; speedup vs baseline: 2.2603x; 2.2603x over previous
//
#include <hip/hip_runtime.h>
#include <hip/hip_fp16.h>

#define BB 32
#define HH 512
#define WW 512
#define NQROW (WW / 4)            // 128 float4 per row
#define NPIX_F 8388608.0f         // 32*512*512
#define QPAD 4

// ---- fused kernel geometry ----
#define RF 16                     // output rows per wave
#define NSTRF (HH / RF)           // 32 stripes
#define NBF (BB * NSTRF * 2)      // 2048 blocks (1 wave each)
#define NROWSF (RF + 30)          // 46 input rows per stripe
#define CQH 64                    // owned quads per column half (256 cols)
#define NQPH (CQH + 2 * QPAD)     // 72 quads incl halo
#define WS_NEED_F ((size_t)NBF * 16)   // 32 KiB of float4 partials

__device__ __forceinline__ void elemwise4(const float h0, const float h1,
                                          const float h2, const float h3,
                                          const float4 t, const float4 p,
                                          float& a_bce, float& a_w,
                                          float& a_i, float& a_u)
{
    const float hv[4] = {h0, h1, h2, h3};
    const float tv[4] = {t.x, t.y, t.z, t.w};
    const float pv[4] = {p.x, p.y, p.z, p.w};
    const float inv961 = (1.0f / 961.0f);
    #pragma unroll
    for (int j = 0; j < 4; ++j) {
        const float ap = hv[j] * inv961;
        const float w  = fmaf(5.0f, fabsf(ap - tv[j]), 1.0f);
        const float pr = pv[j];
        const float ea = __expf(-fabsf(pr));                  // exp(-|pr|)
        const float iv = __builtin_amdgcn_rcpf(1.0f + ea);
        const float pp = (pr >= 0.0f) ? iv : (1.0f - iv);     // sigmoid
        const float sp = fmaxf(pr, 0.0f) + __logf(1.0f + ea); // softplus
        a_bce += sp - pr * tv[j];
        a_w   += w;
        a_i   += pp * tv[j] * w;
        a_u   += (pp + tv[j]) * w;
    }
}

// ---- Fused single pass. NO register arrays in the loop (scratch-proof):
//  * raw-row + t/p prefetch  -> depth-4 scalar shift registers
//  * exiting h-row history   -> LDS (dynamic indexing is native there)
// One wave per (image, 16-row stripe, 256-col half).
__global__ __launch_bounds__(64, 2)
void fused_rows_kernel(const float* __restrict__ pred,
                       const float* __restrict__ targ,
                       float4* __restrict__ part)
{
    const int lane = threadIdx.x;
    const int bi = blockIdx.x;                 // 2048
    const int halfc  = bi & 1;
    const int stripe = (bi >> 1) & (NSTRF - 1);
    const int b      = bi >> 6;
    const int r0  = stripe * RF;
    const int cq0 = halfc * CQH;
    const int q   = cq0 + lane;                // owned quad (global col/4)

    __shared__ float4 ebuf[2][NQPH];           // raw rows, double-buffered
    __shared__ float  locq[2][NQPH];           // per-quad sums
    __shared__ float4 svr[RF][64];             // h-rows 0..15 (exact fp32), 16 KB

    const float4* t4 = (const float4*)(targ + (size_t)b * HH * WW);
    const float4* p4 = (const float4*)(pred + (size_t)b * HH * WW);
    const float4 Z4 = make_float4(0.f, 0.f, 0.f, 0.f);

    // halo quads handled by lanes 0..7 (stateless loads only)
    const int hq = (lane < 4) ? (cq0 - QPAD + lane) : (cq0 + CQH + (lane - 4));
    const bool hq_ok = (lane < 8) && (hq >= 0) && (hq < NQROW);
    const int hslot = (lane < 4) ? lane : (CQH + QPAD + (lane - 4));

    auto ldo = [&](int k) -> float4 {          // owned quad, input row r0-15+k
        const int yy = r0 - 15 + k;
        return (k < NROWSF && yy >= 0 && yy < HH)
                   ? t4[(size_t)yy * NQROW + q] : Z4;
    };
    auto ldh = [&](int k) -> float4 {          // halo quad
        const int yy = r0 - 15 + k;
        return (k < NROWSF && hq_ok && yy >= 0 && yy < HH)
                   ? t4[(size_t)yy * NQROW + hq] : Z4;
    };

    // depth-4 scalar prefetch pipelines (plain variables -> VGPRs, never scratch)
    float4 e0 = ldo(0), e1 = ldo(1), e2 = ldo(2), e3 = ldo(3);
    float4 g0 = ldh(0), g1 = ldh(1), g2 = ldh(2), g3 = ldh(3);
    float4 t0 = Z4, t1 = Z4, t2 = Z4, t3 = Z4;
    float4 p0 = Z4, p1 = Z4, p2 = Z4, p3 = Z4;

    float v0 = 0.f, v1 = 0.f, v2 = 0.f, v3 = 0.f;
    float a_bce = 0.f, a_w = 0.f, a_i = 0.f, a_u = 0.f;

    for (int k = 0; k < NROWSF; ++k) {         // input row r0-15+k
        const float4 e  = e0;  e0 = e1; e1 = e2; e2 = e3; e3 = ldo(k + 4);
        const float4 eh = g0;  g0 = g1; g1 = g2; g2 = g3; g3 = ldh(k + 4);

        // t/p pipeline: issue for output j=k-26 here, consume 4 steps later
        const float4 tc = t0;  t0 = t1; t1 = t2; t2 = t3;
        const float4 pc = p0;  p0 = p1; p1 = p2; p2 = p3;
        if (k >= 26 && k < 26 + RF) {
            const size_t off = (size_t)(r0 + (k - 26)) * NQROW + q;
            t3 = t4[off];
            p3 = p4[off];
        }

        const int bf = k & 1;
        ebuf[bf][QPAD + lane] = e;
        locq[bf][QPAD + lane] = e.x + e.y + e.z + e.w;
        if (lane < 8) {
            ebuf[bf][hslot] = eh;
            locq[bf][hslot] = eh.x + eh.y + eh.z + eh.w;
        }
        __builtin_amdgcn_wave_barrier();       // single-wave LDS exchange

        // horizontal 31-sums for owned cols 4q..4q+3 (pattern verified r1-r6)
        float F = 0.f;
        #pragma unroll
        for (int d = -3; d <= 3; ++d) F += locq[bf][QPAD + lane + d];
        const float4 L = ebuf[bf][lane];
        const float4 U = ebuf[bf][lane + 2 * QPAD];
        const float hs0 = F + L.y + L.z + L.w;
        const float hs1 = F + L.z + L.w + U.x;
        const float hs2 = F + L.w + U.x + U.y;
        const float hs3 = F + U.x + U.y + U.z;

        if (k < RF) svr[k][lane] = make_float4(hs0, hs1, hs2, hs3);
        v0 += hs0; v1 += hs1; v2 += hs2; v3 += hs3;

        if (k >= 30) {
            elemwise4(v0, v1, v2, v3, tc, pc, a_bce, a_w, a_i, a_u);
            const float4 s = svr[k - 30][lane];   // h-row y-15 exits (LDS)
            v0 -= s.x; v1 -= s.y; v2 -= s.z; v3 -= s.w;
        }
    }

    #pragma unroll
    for (int off = 32; off > 0; off >>= 1) {
        a_bce += __shfl_down(a_bce, off, 64);
        a_w   += __shfl_down(a_w,   off, 64);
        a_i   += __shfl_down(a_i,   off, 64);
        a_u   += __shfl_down(a_u,   off, 64);
    }
    if (lane == 0) part[bi] = make_float4(a_bce, a_w, a_i, a_u);
}

// ---- Finalize: 64 partials per image -> per-image sums -> scalar --------
__global__ __launch_bounds__(1024)
void finalize3_kernel(const float4* __restrict__ part, float* __restrict__ out)
{
    const int lane = threadIdx.x & 63;
    const int w    = threadIdx.x >> 6;         // 16 waves, 2 images each
    __shared__ float4 sums[BB];

    #pragma unroll
    for (int s = 0; s < 2; ++s) {
        const int img = w * 2 + s;
        float4 acc = part[img * 64 + lane];    // exactly one partial per lane
        #pragma unroll
        for (int off = 32; off > 0; off >>= 1) {
            acc.x += __shfl_down(acc.x, off, 64);
            acc.y += __shfl_down(acc.y, off, 64);
            acc.z += __shfl_down(acc.z, off, 64);
            acc.w += __shfl_down(acc.w, off, 64);
        }
        if (lane == 0) sums[img] = acc;
    }
    __syncthreads();

    if (w == 0) {
        float bsum = (lane < BB) ? sums[lane].x : 0.f;
        #pragma unroll
        for (int off = 32; off > 0; off >>= 1) bsum += __shfl_down(bsum, off, 64);
        const float bce = __shfl(bsum, 0, 64) * (1.0f / NPIX_F);

        float val = 0.f;
        if (lane < BB) {
            const float wsum  = sums[lane].y;
            const float inter = sums[lane].z;
            const float uni   = sums[lane].w;
            const float w_bce = (wsum * bce + 1e-8f) / (wsum + 1e-8f);
            const float w_iou = 1.0f - (inter + 1.0f + 1e-8f) / (uni - inter + 1.0f + 1e-8f);
            val = w_bce + w_iou;
        }
        #pragma unroll
        for (int off = 32; off > 0; off >>= 1) val += __shfl_down(val, off, 64);
        if (lane == 0) out[0] = val * (1.0f / BB);
    }
}

// ================= fallback (validated round-2 fused path) ===============
#define PADK 15
#define RROWS 32
#define NSTRIPES (HH / RROWS)
#define NCH 2
#define COLS (WW / NCH)
#define CQ (COLS / 4)
#define FNQP (CQ + 2 * QPAD)
#define NSTEPS (RROWS + 2 * PADK)

__global__ __launch_bounds__(64)
void fused_pool_loss_kernel(const float* __restrict__ pred,
                            const float* __restrict__ targ,
                            float* __restrict__ ws)
{
    const int lane = threadIdx.x;
    const int bi   = blockIdx.x;
    const int half   = bi & 1;
    const int stripe = (bi >> 1) & (NSTRIPES - 1);
    const int b      = bi >> 5;
    const int r0  = stripe * RROWS;
    const int cq0 = half * CQ;

    __shared__ __half2 ring[31][2][64];
    __shared__ float4  ebuf[2][FNQP];
    __shared__ float   locq[2][FNQP];

    {
        const __half2 z2 = __floats2half2_rn(0.f, 0.f);
        __half2* rp = &ring[0][0][0];
        for (int i = lane; i < 31 * 2 * 64; i += 64) rp[i] = z2;
    }
    __builtin_amdgcn_wave_barrier();

    const float4* targ4 = (const float4*)(targ + (size_t)b * HH * WW);
    const float4* pred4 = (const float4*)(pred + (size_t)b * HH * WW);
    const float4 Z4 = make_float4(0.f, 0.f, 0.f, 0.f);

    const int hq = (lane < 4) ? (cq0 - QPAD + lane) : (cq0 + CQ + (lane - 4));
    const bool hq_ok = (lane < 8) && (hq >= 0) && (hq < NQROW);
    const int hslot = (lane < 4) ? lane : (CQ + QPAD + (lane - 4));

    auto ld_row = [&](int step, float4& m, float4& h) {
        m = Z4; h = Z4;
        const int yy = r0 - PADK + step;
        if (step < NSTEPS && yy >= 0 && yy < HH) {
            const float4* rp = targ4 + (size_t)yy * NQROW;
            m = rp[cq0 + lane];
            if (hq_ok) h = rp[hq];
        }
    };

    float vacc0 = 0.f, vacc1 = 0.f, vacc2 = 0.f, vacc3 = 0.f;
    float a_bce = 0.f, a_w = 0.f, a_i = 0.f, a_u = 0.f;
    int slot = 0;

    float4 e_p0, e_p1, h_p0, h_p1;
    ld_row(0, e_p0, h_p0);
    ld_row(1, e_p1, h_p1);
    float4 t_p0 = Z4, t_p1 = Z4, p_p0 = Z4, p_p1 = Z4;

    for (int step = 0; step < NSTEPS; ++step) {
        const float4 e  = e_p0;  e_p0 = e_p1;
        const float4 eh = h_p0;  h_p0 = h_p1;
        ld_row(step + 2, e_p1, h_p1);

        const float4 tcur = t_p0, pcur = p_p0;
        t_p0 = t_p1; p_p0 = p_p1;
        {
            const int s2 = step + 2;
            if (s2 >= 2 * PADK && s2 < NSTEPS) {
                const size_t off = (size_t)(r0 + (s2 - 2 * PADK)) * NQROW + cq0 + lane;
                t_p1 = targ4[off];
                p_p1 = pred4[off];
            }
        }

        const int bf = step & 1;
        ebuf[bf][QPAD + lane] = e;
        locq[bf][QPAD + lane] = e.x + e.y + e.z + e.w;
        if (lane < 8) {
            ebuf[bf][hslot] = eh;
            locq[bf][hslot] = eh.x + eh.y + eh.z + eh.w;
        }
        __builtin_amdgcn_wave_barrier();

        float F = 0.f;
        #pragma unroll
        for (int k = -3; k <= 3; ++k) F += locq[bf][lane + QPAD + k];
        const float4 L = ebuf[bf][lane];
        const float4 U = ebuf[bf][lane + 2 * QPAD];
        const float h0 = F + L.y + L.z + L.w;
        const float h1 = F + L.z + L.w + U.x;
        const float h2 = F + L.w + U.x + U.y;
        const float h3 = F + U.x + U.y + U.z;

        const __half2 n01 = __floats2half2_rn(h0, h1);
        const __half2 n23 = __floats2half2_rn(h2, h3);
        const __half2 o01 = ring[slot][0][lane];
        const __half2 o23 = ring[slot][1][lane];
        ring[slot][0][lane] = n01;
        ring[slot][1][lane] = n23;
        const float2 nf01 = __half22float2(n01), nf23 = __half22float2(n23);
        const float2 of01 = __half22float2(o01), of23 = __half22float2(o23);
        vacc0 += nf01.x - of01.x;
        vacc1 += nf01.y - of01.y;
        vacc2 += nf23.x - of23.x;
        vacc3 += nf23.y - of23.y;
        slot = (slot == 30) ? 0 : (slot + 1);

        if (step >= 2 * PADK) {
            elemwise4(vacc0, vacc1, vacc2, vacc3, tcur, pcur, a_bce, a_w, a_i, a_u);
        }
    }

    #pragma unroll
    for (int off = 32; off > 0; off >>= 1) {
        a_bce += __shfl_down(a_bce, off, 64);
        a_w   += __shfl_down(a_w,   off, 64);
        a_i   += __shfl_down(a_i,   off, 64);
        a_u   += __shfl_down(a_u,   off, 64);
    }
    if (lane == 0) {
        atomicAdd(&ws[0],      a_bce);
        atomicAdd(&ws[1 + b],  a_w);
        atomicAdd(&ws[33 + b], a_i);
        atomicAdd(&ws[65 + b], a_u);
    }
}

__global__ void finalize_kernel(const float* __restrict__ ws, float* __restrict__ out)
{
    const int i = threadIdx.x;
    float val = 0.f;
    if (i < BB) {
        const float bce   = ws[0] * (1.0f / NPIX_F);
        const float wsum  = ws[1 + i];
        const float inter = ws[33 + i];
        const float uni   = ws[65 + i];
        const float w_bce = (wsum * bce + 1e-8f) / (wsum + 1e-8f);
        const float w_iou = 1.0f - (inter + 1.0f + 1e-8f) / (uni - inter + 1.0f + 1e-8f);
        val = w_bce + w_iou;
    }
    #pragma unroll
    for (int off = 32; off > 0; off >>= 1) val += __shfl_down(val, off, 64);
    if (i == 0) out[0] = val * (1.0f / BB);
}

extern "C" void kernel_launch(void* const* d_in, const int* in_sizes, int n_in,
                              void* d_out, int out_size, void* d_ws, size_t ws_size,
                              hipStream_t stream)
{
    (void)in_sizes; (void)n_in; (void)out_size;
    const float* pred = (const float*)d_in[0];   // y_pred
    const float* targ = (const float*)d_in[1];   // y_target
    float* out = (float*)d_out;

    if (ws_size >= WS_NEED_F) {
        float4* part = (float4*)d_ws;
        hipLaunchKernelGGL(fused_rows_kernel, dim3(NBF), dim3(64), 0, stream,
                           pred, targ, part);
        hipLaunchKernelGGL(finalize3_kernel, dim3(1), dim3(1024), 0, stream,
                           part, out);
    } else {
        float* ws = (float*)d_ws;
        hipMemsetAsync(ws, 0, 97 * sizeof(float), stream);
        hipLaunchKernelGGL(fused_pool_loss_kernel,
                           dim3(BB * NSTRIPES * NCH), dim3(64), 0, stream,
                           pred, targ, ws);
        hipLaunchKernelGGL(finalize_kernel, dim3(1), dim3(64), 0, stream, ws, out);
    }
}

// Round 9
// 131.088 us; speedup vs baseline: 2.2631x; 1.0012x over previous
//
#include <hip/hip_runtime.h>
#include <hip/hip_fp16.h>

#define BB 32
#define HH 512
#define WW 512
#define NQROW (WW / 4)            // 128 float4 per row
#define NPIX_F 8388608.0f         // 32*512*512
#define QPAD 4

// ---- fused kernel geometry ----
#define RF 16                     // output rows per wave
#define NSTRF (HH / RF)           // 32 stripes
#define NBF (BB * NSTRF * 2)      // 2048 blocks (1 wave each)
#define NROWSF (RF + 30)          // 46 input rows per stripe
#define CQH 64                    // owned quads per column half (256 cols)
#define NQPH (CQH + 2 * QPAD)     // 72 quads incl halo
#define WS_NEED_F ((size_t)NBF * 16)   // 32 KiB of float4 partials

__device__ __forceinline__ void elemwise4(const float h0, const float h1,
                                          const float h2, const float h3,
                                          const float4 t, const float4 p,
                                          float& a_bce, float& a_w,
                                          float& a_i, float& a_u)
{
    const float hv[4] = {h0, h1, h2, h3};
    const float tv[4] = {t.x, t.y, t.z, t.w};
    const float pv[4] = {p.x, p.y, p.z, p.w};
    const float inv961 = (1.0f / 961.0f);
    #pragma unroll
    for (int j = 0; j < 4; ++j) {
        const float ap = hv[j] * inv961;
        const float w  = fmaf(5.0f, fabsf(ap - tv[j]), 1.0f);
        const float pr = pv[j];
        const float ea = __expf(-fabsf(pr));                  // exp(-|pr|)
        const float iv = __builtin_amdgcn_rcpf(1.0f + ea);
        const float pp = (pr >= 0.0f) ? iv : (1.0f - iv);     // sigmoid
        const float sp = fmaxf(pr, 0.0f) + __logf(1.0f + ea); // softplus
        a_bce += sp - pr * tv[j];
        a_w   += w;
        a_i   += pp * tv[j] * w;
        a_u   += (pp + tv[j]) * w;
    }
}

// ---- Fused single pass, occupancy-tuned (4 waves/SIMD):
//  * single-buffer LDS exchange (one wave per block -> no cross-wave hazard;
//    same-object LDS ordering by the memory legalizer, as rounds 2-8)
//  * h-row exit history in fp16 LDS: v accumulates the ROUNDED value and
//    subtracts the SAME rounded value on exit (exact cancellation; validated
//    rounds 1-2, absmax 0.0)
//  * raw-row + t/p prefetch as depth-4 scalar shift registers (scratch-proof)
// LDS ~9.6 KB -> 16 blocks/CU.
__global__ __launch_bounds__(64, 4)
void fused_rows_kernel(const float* __restrict__ pred,
                       const float* __restrict__ targ,
                       float4* __restrict__ part)
{
    const int lane = threadIdx.x;
    const int bi = blockIdx.x;                 // 2048
    const int halfc  = bi & 1;
    const int stripe = (bi >> 1) & (NSTRF - 1);
    const int b      = bi >> 6;
    const int r0  = stripe * RF;
    const int cq0 = halfc * CQH;
    const int q   = cq0 + lane;                // owned quad (global col/4)

    __shared__ float4 ebuf[NQPH];              // raw row (single buffer), 1152 B
    __shared__ float  locq[NQPH];              // per-quad sums, 288 B
    __shared__ uint2  svr[RF][64];             // h-rows 0..15 as 4x fp16, 8 KB

    const float4* t4 = (const float4*)(targ + (size_t)b * HH * WW);
    const float4* p4 = (const float4*)(pred + (size_t)b * HH * WW);
    const float4 Z4 = make_float4(0.f, 0.f, 0.f, 0.f);

    // halo quads handled by lanes 0..7 (stateless loads only)
    const int hq = (lane < 4) ? (cq0 - QPAD + lane) : (cq0 + CQH + (lane - 4));
    const bool hq_ok = (lane < 8) && (hq >= 0) && (hq < NQROW);
    const int hslot = (lane < 4) ? lane : (CQH + QPAD + (lane - 4));

    auto ldo = [&](int k) -> float4 {          // owned quad, input row r0-15+k
        const int yy = r0 - 15 + k;
        return (k < NROWSF && yy >= 0 && yy < HH)
                   ? t4[(size_t)yy * NQROW + q] : Z4;
    };
    auto ldh = [&](int k) -> float4 {          // halo quad
        const int yy = r0 - 15 + k;
        return (k < NROWSF && hq_ok && yy >= 0 && yy < HH)
                   ? t4[(size_t)yy * NQROW + hq] : Z4;
    };

    // depth-4 scalar prefetch pipelines (plain variables -> VGPRs, never scratch)
    float4 e0 = ldo(0), e1 = ldo(1), e2 = ldo(2), e3 = ldo(3);
    float4 g0 = ldh(0), g1 = ldh(1), g2 = ldh(2), g3 = ldh(3);
    float4 t0 = Z4, t1 = Z4, t2 = Z4, t3 = Z4;
    float4 p0 = Z4, p1 = Z4, p2 = Z4, p3 = Z4;

    float v0 = 0.f, v1 = 0.f, v2 = 0.f, v3 = 0.f;
    float a_bce = 0.f, a_w = 0.f, a_i = 0.f, a_u = 0.f;

    for (int k = 0; k < NROWSF; ++k) {         // input row r0-15+k
        const float4 e  = e0;  e0 = e1; e1 = e2; e2 = e3; e3 = ldo(k + 4);
        const float4 eh = g0;  g0 = g1; g1 = g2; g2 = g3; g3 = ldh(k + 4);

        // t/p pipeline: issue for output j=k-26 here, consume 4 steps later
        const float4 tc = t0;  t0 = t1; t1 = t2; t2 = t3;
        const float4 pc = p0;  p0 = p1; p1 = p2; p2 = p3;
        if (k >= 26 && k < 26 + RF) {
            const size_t off = (size_t)(r0 + (k - 26)) * NQROW + q;
            t3 = t4[off];
            p3 = p4[off];
        }

        ebuf[QPAD + lane] = e;
        locq[QPAD + lane] = e.x + e.y + e.z + e.w;
        if (lane < 8) {
            ebuf[hslot] = eh;
            locq[hslot] = eh.x + eh.y + eh.z + eh.w;
        }
        __builtin_amdgcn_wave_barrier();       // writes before reads (sched)

        // horizontal 31-sums for owned cols 4q..4q+3 (pattern verified r1-r8)
        float F = 0.f;
        #pragma unroll
        for (int d = -3; d <= 3; ++d) F += locq[QPAD + lane + d];
        const float4 L = ebuf[lane];
        const float4 U = ebuf[lane + 2 * QPAD];
        const float hs0 = F + L.y + L.z + L.w;
        const float hs1 = F + L.z + L.w + U.x;
        const float hs2 = F + L.w + U.x + U.y;
        const float hs3 = F + U.x + U.y + U.z;
        __builtin_amdgcn_wave_barrier();       // reads before next-step writes

        if (k < RF) {
            // quantize once; add the SAME rounded value that will be
            // subtracted at exit -> exact cancellation, no drift
            const __half2 q01 = __floats2half2_rn(hs0, hs1);
            const __half2 q23 = __floats2half2_rn(hs2, hs3);
            uint2 pk;
            pk.x = __builtin_bit_cast(unsigned int, q01);
            pk.y = __builtin_bit_cast(unsigned int, q23);
            svr[k][lane] = pk;
            const float2 f01 = __half22float2(q01);
            const float2 f23 = __half22float2(q23);
            v0 += f01.x; v1 += f01.y; v2 += f23.x; v3 += f23.y;
        } else {
            // rows that never exit within this stripe: add exact
            v0 += hs0; v1 += hs1; v2 += hs2; v3 += hs3;
        }

        if (k >= 30) {
            elemwise4(v0, v1, v2, v3, tc, pc, a_bce, a_w, a_i, a_u);
            const uint2 pk = svr[k - 30][lane];    // h-row y-15 exits
            const float2 f01 = __half22float2(__builtin_bit_cast(__half2, pk.x));
            const float2 f23 = __half22float2(__builtin_bit_cast(__half2, pk.y));
            v0 -= f01.x; v1 -= f01.y; v2 -= f23.x; v3 -= f23.y;
        }
    }

    #pragma unroll
    for (int off = 32; off > 0; off >>= 1) {
        a_bce += __shfl_down(a_bce, off, 64);
        a_w   += __shfl_down(a_w,   off, 64);
        a_i   += __shfl_down(a_i,   off, 64);
        a_u   += __shfl_down(a_u,   off, 64);
    }
    if (lane == 0) part[bi] = make_float4(a_bce, a_w, a_i, a_u);
}

// ---- Finalize: 64 partials per image -> per-image sums -> scalar --------
__global__ __launch_bounds__(1024)
void finalize3_kernel(const float4* __restrict__ part, float* __restrict__ out)
{
    const int lane = threadIdx.x & 63;
    const int w    = threadIdx.x >> 6;         // 16 waves, 2 images each
    __shared__ float4 sums[BB];

    #pragma unroll
    for (int s = 0; s < 2; ++s) {
        const int img = w * 2 + s;
        float4 acc = part[img * 64 + lane];    // exactly one partial per lane
        #pragma unroll
        for (int off = 32; off > 0; off >>= 1) {
            acc.x += __shfl_down(acc.x, off, 64);
            acc.y += __shfl_down(acc.y, off, 64);
            acc.z += __shfl_down(acc.z, off, 64);
            acc.w += __shfl_down(acc.w, off, 64);
        }
        if (lane == 0) sums[img] = acc;
    }
    __syncthreads();

    if (w == 0) {
        float bsum = (lane < BB) ? sums[lane].x : 0.f;
        #pragma unroll
        for (int off = 32; off > 0; off >>= 1) bsum += __shfl_down(bsum, off, 64);
        const float bce = __shfl(bsum, 0, 64) * (1.0f / NPIX_F);

        float val = 0.f;
        if (lane < BB) {
            const float wsum  = sums[lane].y;
            const float inter = sums[lane].z;
            const float uni   = sums[lane].w;
            const float w_bce = (wsum * bce + 1e-8f) / (wsum + 1e-8f);
            const float w_iou = 1.0f - (inter + 1.0f + 1e-8f) / (uni - inter + 1.0f + 1e-8f);
            val = w_bce + w_iou;
        }
        #pragma unroll
        for (int off = 32; off > 0; off >>= 1) val += __shfl_down(val, off, 64);
        if (lane == 0) out[0] = val * (1.0f / BB);
    }
}

// ================= fallback (validated round-2 fused path) ===============
#define PADK 15
#define RROWS 32
#define NSTRIPES (HH / RROWS)
#define NCH 2
#define COLS (WW / NCH)
#define CQ (COLS / 4)
#define FNQP (CQ + 2 * QPAD)
#define NSTEPS (RROWS + 2 * PADK)

__global__ __launch_bounds__(64)
void fused_pool_loss_kernel(const float* __restrict__ pred,
                            const float* __restrict__ targ,
                            float* __restrict__ ws)
{
    const int lane = threadIdx.x;
    const int bi   = blockIdx.x;
    const int half   = bi & 1;
    const int stripe = (bi >> 1) & (NSTRIPES - 1);
    const int b      = bi >> 5;
    const int r0  = stripe * RROWS;
    const int cq0 = half * CQ;

    __shared__ __half2 ring[31][2][64];
    __shared__ float4  ebuf[2][FNQP];
    __shared__ float   locq[2][FNQP];

    {
        const __half2 z2 = __floats2half2_rn(0.f, 0.f);
        __half2* rp = &ring[0][0][0];
        for (int i = lane; i < 31 * 2 * 64; i += 64) rp[i] = z2;
    }
    __builtin_amdgcn_wave_barrier();

    const float4* targ4 = (const float4*)(targ + (size_t)b * HH * WW);
    const float4* pred4 = (const float4*)(pred + (size_t)b * HH * WW);
    const float4 Z4 = make_float4(0.f, 0.f, 0.f, 0.f);

    const int hq = (lane < 4) ? (cq0 - QPAD + lane) : (cq0 + CQ + (lane - 4));
    const bool hq_ok = (lane < 8) && (hq >= 0) && (hq < NQROW);
    const int hslot = (lane < 4) ? lane : (CQ + QPAD + (lane - 4));

    auto ld_row = [&](int step, float4& m, float4& h) {
        m = Z4; h = Z4;
        const int yy = r0 - PADK + step;
        if (step < NSTEPS && yy >= 0 && yy < HH) {
            const float4* rp = targ4 + (size_t)yy * NQROW;
            m = rp[cq0 + lane];
            if (hq_ok) h = rp[hq];
        }
    };

    float vacc0 = 0.f, vacc1 = 0.f, vacc2 = 0.f, vacc3 = 0.f;
    float a_bce = 0.f, a_w = 0.f, a_i = 0.f, a_u = 0.f;
    int slot = 0;

    float4 e_p0, e_p1, h_p0, h_p1;
    ld_row(0, e_p0, h_p0);
    ld_row(1, e_p1, h_p1);
    float4 t_p0 = Z4, t_p1 = Z4, p_p0 = Z4, p_p1 = Z4;

    for (int step = 0; step < NSTEPS; ++step) {
        const float4 e  = e_p0;  e_p0 = e_p1;
        const float4 eh = h_p0;  h_p0 = h_p1;
        ld_row(step + 2, e_p1, h_p1);

        const float4 tcur = t_p0, pcur = p_p0;
        t_p0 = t_p1; p_p0 = p_p1;
        {
            const int s2 = step + 2;
            if (s2 >= 2 * PADK && s2 < NSTEPS) {
                const size_t off = (size_t)(r0 + (s2 - 2 * PADK)) * NQROW + cq0 + lane;
                t_p1 = targ4[off];
                p_p1 = pred4[off];
            }
        }

        const int bf = step & 1;
        ebuf[bf][QPAD + lane] = e;
        locq[bf][QPAD + lane] = e.x + e.y + e.z + e.w;
        if (lane < 8) {
            ebuf[bf][hslot] = eh;
            locq[bf][hslot] = eh.x + eh.y + eh.z + eh.w;
        }
        __builtin_amdgcn_wave_barrier();

        float F = 0.f;
        #pragma unroll
        for (int k = -3; k <= 3; ++k) F += locq[bf][lane + QPAD + k];
        const float4 L = ebuf[bf][lane];
        const float4 U = ebuf[bf][lane + 2 * QPAD];
        const float h0 = F + L.y + L.z + L.w;
        const float h1 = F + L.z + L.w + U.x;
        const float h2 = F + L.w + U.x + U.y;
        const float h3 = F + U.x + U.y + U.z;

        const __half2 n01 = __floats2half2_rn(h0, h1);
        const __half2 n23 = __floats2half2_rn(h2, h3);
        const __half2 o01 = ring[slot][0][lane];
        const __half2 o23 = ring[slot][1][lane];
        ring[slot][0][lane] = n01;
        ring[slot][1][lane] = n23;
        const float2 nf01 = __half22float2(n01), nf23 = __half22float2(n23);
        const float2 of01 = __half22float2(o01), of23 = __half22float2(o23);
        vacc0 += nf01.x - of01.x;
        vacc1 += nf01.y - of01.y;
        vacc2 += nf23.x - of23.x;
        vacc3 += nf23.y - of23.y;
        slot = (slot == 30) ? 0 : (slot + 1);

        if (step >= 2 * PADK) {
            elemwise4(vacc0, vacc1, vacc2, vacc3, tcur, pcur, a_bce, a_w, a_i, a_u);
        }
    }

    #pragma unroll
    for (int off = 32; off > 0; off >>= 1) {
        a_bce += __shfl_down(a_bce, off, 64);
        a_w   += __shfl_down(a_w,   off, 64);
        a_i   += __shfl_down(a_i,   off, 64);
        a_u   += __shfl_down(a_u,   off, 64);
    }
    if (lane == 0) {
        atomicAdd(&ws[0],      a_bce);
        atomicAdd(&ws[1 + b],  a_w);
        atomicAdd(&ws[33 + b], a_i);
        atomicAdd(&ws[65 + b], a_u);
    }
}

__global__ void finalize_kernel(const float* __restrict__ ws, float* __restrict__ out)
{
    const int i = threadIdx.x;
    float val = 0.f;
    if (i < BB) {
        const float bce   = ws[0] * (1.0f / NPIX_F);
        const float wsum  = ws[1 + i];
        const float inter = ws[33 + i];
        const float uni   = ws[65 + i];
        const float w_bce = (wsum * bce + 1e-8f) / (wsum + 1e-8f);
        const float w_iou = 1.0f - (inter + 1.0f + 1e-8f) / (uni - inter + 1.0f + 1e-8f);
        val = w_bce + w_iou;
    }
    #pragma unroll
    for (int off = 32; off > 0; off >>= 1) val += __shfl_down(val, off, 64);
    if (i == 0) out[0] = val * (1.0f / BB);
}

extern "C" void kernel_launch(void* const* d_in, const int* in_sizes, int n_in,
                              void* d_out, int out_size, void* d_ws, size_t ws_size,
                              hipStream_t stream)
{
    (void)in_sizes; (void)n_in; (void)out_size;
    const float* pred = (const float*)d_in[0];   // y_pred
    const float* targ = (const float*)d_in[1];   // y_target
    float* out = (float*)d_out;

    if (ws_size >= WS_NEED_F) {
        float4* part = (float4*)d_ws;
        hipLaunchKernelGGL(fused_rows_kernel, dim3(NBF), dim3(64), 0, stream,
                           pred, targ, part);
        hipLaunchKernelGGL(finalize3_kernel, dim3(1), dim3(1024), 0, stream,
                           part, out);
    } else {
        float* ws = (float*)d_ws;
        hipMemsetAsync(ws, 0, 97 * sizeof(float), stream);
        hipLaunchKernelGGL(fused_pool_loss_kernel,
                           dim3(BB * NSTRIPES * NCH), dim3(64), 0, stream,
                           pred, targ, ws);
        hipLaunchKernelGGL(finalize_kernel, dim3(1), dim3(64), 0, stream, ws, out);
    }
}